// Round 2
// baseline (352.773 us; speedup 1.0000x reference)
//
#include <hip/hip_runtime.h>
#include <math.h>

#define B_     1024
#define T_     80
#define D_     512
#define C_     78      // VOCAB+1
#define PRED_  30
#define BLANK_ 77
#define NKK    16      // 512 / 32
#define FRAG   512     // ushorts per fragment block (64 lanes * 8 halves)
#define PLANE_STRIDE (5 * NKK * FRAG)   // 40960 ushorts per plane

typedef __attribute__((ext_vector_type(8))) _Float16 f16x8;
typedef __attribute__((ext_vector_type(4))) float    f32x4;

// Split W [512,78] fp32 into two f16 planes (w1 = rnd(w), w2 = rnd(w - w1)),
// fragment-linear: [plane][ct][kk][lane][j] -> main-loop B load = base + lane*16B.
__global__ __launch_bounds__(256) void prep_w(const float* __restrict__ W,
                                              ushort* __restrict__ Wf) {
    int i = blockIdx.x * 256 + threadIdx.x;
    if (i >= 2 * PLANE_STRIDE) return;
    int j    = i & 7;
    int lane = (i >> 3) & 63;
    int kk   = (i >> 9) & 15;
    int rest = i >> 13;          // plane*5 + ct
    int ct   = rest % 5;
    int plane = rest / 5;
    int q = lane >> 4, n = lane & 15;
    int k = kk * 32 + q * 8 + j;
    int c = ct * 16 + n;
    float v = (c < C_) ? W[k * C_ + c] : 0.f;
    _Float16 h1 = (_Float16)v;
    union { _Float16 h; ushort u; } cv;
    cv.h = (plane == 0) ? h1 : (_Float16)(v - (float)h1);
    Wf[i] = cv.u;
}

// Block = 320 threads (5 waves) = ONE batch element (80 rows).
// Wave w owns column-tile ct = w (cols w*16..w*16+15) for ALL 5 row-tiles.
//   -> B plane-1 fragments for the whole K-loop live in 64 VGPRs (loaded once).
//   -> B plane-2 (residual) is ONE 16B load per K-step, prefetched depth-2.
//   -> A: direct global->reg, rolling ring of 5 tiles (10 float4 in flight).
// No barriers / no LDS in the main loop. Epilogue does a 2-barrier cross-wave
// reduction (max / argmax / expsum per row across the 5 ct-waves).
__global__ __launch_bounds__(320, 3) void gemm_ctc(
    const float* __restrict__ feat,   // [81920, 512] fp32
    const ushort* __restrict__ Wf,    // f16 split planes, fragment-linear
    const float* __restrict__ bias,   // [78] fp32
    float* __restrict__ probs,        // [81920, 78] fp32
    float* __restrict__ lab)          // [1024, 30] fp32
{
    __shared__ float mxs[5][T_];
    __shared__ float sms[5][T_];
    __shared__ int   ais[5][T_];
    __shared__ int   best_s[T_];

    const int tid  = threadIdx.x;
    const int w    = tid >> 6;      // wave id == ct
    const int lane = tid & 63;
    const int q    = lane >> 4;
    const int n    = lane & 15;

    // ---- B plane-1 for ct=w: 16 fragments into registers ----
    const ushort* bp1 = Wf + (size_t)(w * NKK) * FRAG + lane * 8;
    f16x8 b1r[NKK];
    #pragma unroll
    for (int kk = 0; kk < NKK; ++kk)
        b1r[kk] = *(const f16x8*)(bp1 + kk * FRAG);

    // ---- B plane-2 (residual): depth-2 prefetch ----
    const ushort* bp2 = bp1 + PLANE_STRIDE;
    f16x8 b2a = *(const f16x8*)(bp2);
    f16x8 b2b = *(const f16x8*)(bp2 + FRAG);

    // ---- A rolling ring: 5 row-tiles, one kk-slice each in flight ----
    // lane reads its own 32B: A[row = rt*16 + n][kk*32 + q*8 .. +8]
    const float* Ab = feat + ((size_t)blockIdx.x * T_ + n) * D_ + q * 8;
    float4 bufA[5], bufB[5];
    #pragma unroll
    for (int rt = 0; rt < 5; ++rt) {
        bufA[rt] = *(const float4*)(Ab + rt * 16 * D_);
        bufB[rt] = *(const float4*)(Ab + rt * 16 * D_ + 4);
    }

    f32x4 acc[5];
    #pragma unroll
    for (int rt = 0; rt < 5; ++rt)
        acc[rt] = (f32x4){0.f, 0.f, 0.f, 0.f};

    #pragma unroll
    for (int kk = 0; kk < NKK; ++kk) {
        f16x8 b2c = b2a;
        b2a = b2b;
        if (kk < NKK - 2) b2b = *(const f16x8*)(bp2 + (kk + 2) * FRAG);

        #pragma unroll
        for (int rt = 0; rt < 5; ++rt) {
            float4 f0 = bufA[rt], f1 = bufB[rt];
            if (kk < NKK - 1) {
                const float* p = Ab + rt * 16 * D_ + (kk + 1) * 32;
                bufA[rt] = *(const float4*)(p);
                bufB[rt] = *(const float4*)(p + 4);
            }
            float v[8] = {f0.x, f0.y, f0.z, f0.w, f1.x, f1.y, f1.z, f1.w};
            f16x8 a1f, a2f;
            #pragma unroll
            for (int j = 0; j < 8; ++j) {
                _Float16 h = (_Float16)v[j];
                a1f[j] = h;
                a2f[j] = (_Float16)(v[j] - (float)h);
            }
            acc[rt] = __builtin_amdgcn_mfma_f32_16x16x32_f16(a1f, b1r[kk], acc[rt], 0, 0, 0);
            acc[rt] = __builtin_amdgcn_mfma_f32_16x16x32_f16(a2f, b1r[kk], acc[rt], 0, 0, 0);
            acc[rt] = __builtin_amdgcn_mfma_f32_16x16x32_f16(a1f, b2c,     acc[rt], 0, 0, 0);
        }
    }

    // ---- epilogue ----
    // This lane's column and validity (wave 4, n>=14 -> col>=78 invalid)
    const int  colc   = w * 16 + n;
    const bool cvalid = (colc < C_);
    const float bv    = cvalid ? bias[colc] : 0.f;

    // x[rt][r]: row = rt*16 + q*4 + r, col = colc
    float x[5][4];
    #pragma unroll
    for (int rt = 0; rt < 5; ++rt)
        #pragma unroll
        for (int r = 0; r < 4; ++r)
            x[rt][r] = cvalid ? (acc[rt][r] + bv) : -INFINITY;

    // Phase A: per-(row, ct) max + argmax over the 16 cols this wave owns
    #pragma unroll
    for (int rt = 0; rt < 5; ++rt) {
        float av[4]; int ai[4];
        #pragma unroll
        for (int r = 0; r < 4; ++r) { av[r] = x[rt][r]; ai[r] = colc; }
        #pragma unroll
        for (int off = 8; off >= 1; off >>= 1) {
            #pragma unroll
            for (int r = 0; r < 4; ++r) {
                float ov = __shfl_xor(av[r], off, 16);
                int   oi = __shfl_xor(ai[r], off, 16);
                if (ov > av[r] || (ov == av[r] && oi < ai[r])) { av[r] = ov; ai[r] = oi; }
            }
        }
        if (n == 0) {
            int row = rt * 16 + q * 4;
            #pragma unroll
            for (int r = 0; r < 4; ++r) {
                mxs[w][row + r] = av[r];
                ais[w][row + r] = ai[r];
            }
        }
    }
    __syncthreads();

    // global argmax per row (ct ascending -> ties pick lowest class index)
    if (tid < T_) {
        float m = mxs[0][tid]; int idx = ais[0][tid];
        #pragma unroll
        for (int ct = 1; ct < 5; ++ct) {
            float mv = mxs[ct][tid];
            if (mv > m) { m = mv; idx = ais[ct][tid]; }
        }
        best_s[tid] = idx;
    }

    // Phase B: exp with global max, partial sums per (row, ct)
    float e[5][4];
    #pragma unroll
    for (int rt = 0; rt < 5; ++rt) {
        int row = rt * 16 + q * 4;
        float s[4] = {0.f, 0.f, 0.f, 0.f};
        #pragma unroll
        for (int r = 0; r < 4; ++r) {
            float gm = mxs[0][row + r];
            #pragma unroll
            for (int ct = 1; ct < 5; ++ct) gm = fmaxf(gm, mxs[ct][row + r]);
            e[rt][r] = __expf(x[rt][r] - gm);   // -INF -> 0
            s[r] = e[rt][r];
        }
        #pragma unroll
        for (int off = 8; off >= 1; off >>= 1)
            #pragma unroll
            for (int r = 0; r < 4; ++r) s[r] += __shfl_xor(s[r], off, 16);
        if (n == 0) {
            #pragma unroll
            for (int r = 0; r < 4; ++r) sms[w][row + r] = s[r];
        }
    }
    __syncthreads();

    // Phase C: normalize + store this wave's 16 columns of each row
    #pragma unroll
    for (int rt = 0; rt < 5; ++rt) {
        int row = rt * 16 + q * 4;
        #pragma unroll
        for (int r = 0; r < 4; ++r) {
            float tot = sms[0][row + r];
            #pragma unroll
            for (int ct = 1; ct < 5; ++ct) tot += sms[ct][row + r];
            float inv = 1.f / tot;
            if (cvalid) {
                float* op = probs + ((size_t)blockIdx.x * T_ + row + r) * C_ + colc;
                __builtin_nontemporal_store(e[rt][r] * inv, op);
            }
        }
    }

    // in-block CTC greedy decode (1 batch element)
    if (tid == 0) {
        float* op = lab + (size_t)blockIdx.x * PRED_;
        int prev = -1, pos = 0;
        for (int t2 = 0; t2 < T_; ++t2) {
            int v = best_s[t2];
            if (v != BLANK_ && v != prev) {
                if (pos < PRED_) op[pos] = (float)v;
                ++pos;
            }
            prev = v;
        }
        for (int i2 = (pos < PRED_ ? pos : PRED_); i2 < PRED_; ++i2) op[i2] = -1.f;
    }
}

extern "C" void kernel_launch(void* const* d_in, const int* in_sizes, int n_in,
                              void* d_out, int out_size, void* d_ws, size_t ws_size,
                              hipStream_t stream) {
    const float* feat = (const float*)d_in[0];   // fp32 [1024,80,512]
    const float* W    = (const float*)d_in[1];   // fp32 [512,78]
    const float* bias = (const float*)d_in[2];   // fp32 [78]
    // d_in[3]=y, d_in[4]=times : unused
    float*  probs = (float*)d_out;
    float*  lab   = probs + (size_t)B_ * T_ * C_;
    ushort* Wf    = (ushort*)d_ws;               // 163840 B scratch

    hipLaunchKernelGGL(prep_w, dim3(320), dim3(256), 0, stream, W, Wf);
    hipLaunchKernelGGL(gemm_ctc, dim3(B_), dim3(320), 0, stream,
                       feat, Wf, bias, probs, lab);
}

// Round 3
// 271.237 us; speedup vs baseline: 1.3006x; 1.3006x over previous
//
#include <hip/hip_runtime.h>
#include <math.h>

#define B_     1024
#define T_     80
#define D_     512
#define C_     78      // VOCAB+1
#define PRED_  30
#define BLANK_ 77
#define NKK    16      // 512 / 32
#define FRAG   512     // ushorts per fragment block (64 lanes * 8 halves)
#define PLANE_STRIDE (5 * NKK * FRAG)   // 40960 ushorts per plane
#define ROWS_PB 160    // rows per block (2 batch elements)
#define A_BYTES (ROWS_PB * 128)         // 20480 B per A slice (160 rows x 32 f32)
#define SLICE_BYTES (A_BYTES + 10 * 1024)  // + 10 B-fragments (5ct x 2 planes)

typedef __attribute__((ext_vector_type(8))) _Float16 f16x8;
typedef __attribute__((ext_vector_type(4))) float    f32x4;

#define WAITVM(N) asm volatile("s_waitcnt vmcnt(" #N ")" ::: "memory")

__device__ __forceinline__ void load_lds16(const void* g, void* l) {
    __builtin_amdgcn_global_load_lds(
        (const __attribute__((address_space(1))) unsigned int*)g,
        (__attribute__((address_space(3))) unsigned int*)l, 16, 0, 0);
}

// Split W [512,78] fp32 into two f16 planes (w1 = rnd(w), w2 = rnd(w - w1)),
// fragment-linear: [plane][ct][kk][lane][j] -> stage load = base + lane*16B.
__global__ __launch_bounds__(256) void prep_w(const float* __restrict__ W,
                                              ushort* __restrict__ Wf) {
    int i = blockIdx.x * 256 + threadIdx.x;
    if (i >= 2 * PLANE_STRIDE) return;
    int j    = i & 7;
    int lane = (i >> 3) & 63;
    int kk   = (i >> 9) & 15;
    int rest = i >> 13;          // plane*5 + ct
    int ct   = rest % 5;
    int plane = rest / 5;
    int q = lane >> 4, n = lane & 15;
    int k = kk * 32 + q * 8 + j;
    int c = ct * 16 + n;
    float v = (c < C_) ? W[k * C_ + c] : 0.f;
    _Float16 h1 = (_Float16)v;
    union { _Float16 h; ushort u; } cv;
    cv.h = (plane == 0) ? h1 : (_Float16)(v - (float)h1);
    Wf[i] = cv.u;
}

// Block = 320 threads (5 waves) = 2 batch elements (160 rows). Wave w: rows
// [w*32, w*32+32) as two 16-row MFMA tiles, all 78 (pad 80) cols.
// PIPELINE (T3/T4): each K-slice (A rows + that kk's 10 B fragments) is staged
// into LDS with global_load_lds, triple-buffered, 2 slices ahead. The vmem
// queue is a pure in-order stream of slice stages, so `s_waitcnt vmcnt(6)`
// retires exactly slice k while k+1 (and k+2 mid-flight) stay outstanding
// ACROSS the raw s_barrier — no drain-to-0 in the main loop.
__global__ __launch_bounds__(320) void gemm_ctc(
    const float* __restrict__ feat,   // [81920, 512] fp32
    const ushort* __restrict__ Wf,    // f16 split planes, fragment-linear
    const float* __restrict__ bias,   // [78] fp32
    float* __restrict__ probs,        // [81920, 78] fp32
    float* __restrict__ lab)          // [1024, 30] fp32
{
    __shared__ __align__(16) unsigned char Sbuf[3][SLICE_BYTES];  // 3 x 30 KB
    __shared__ int best_s[2][T_];

    const int tid  = threadIdx.x;
    const int w    = tid >> 6;
    const int lane = tid & 63;
    const int q    = lane >> 4;
    const int n    = lane & 15;

    const float* Abase = feat + (size_t)blockIdx.x * ROWS_PB * D_;

    // stage slice kk into buffer buf: A = 160x32 f32 (XOR-swizzled chunks:
    // LDS chunk pos (row,p) holds global chunk p ^ (row&7)); B = 10 x 1KB
    // fragments (slot f = plane*5+ct), linear.
    auto stage = [&](int buf, int kk) {
        #pragma unroll
        for (int l = 0; l < 4; ++l) {
            int rb  = w * 4 + l;             // 0..19 (8-row groups)
            int row = rb * 8 + (lane >> 3);
            int pc  = lane & 7;
            int sc  = pc ^ (row & 7);
            const float* g = Abase + (size_t)row * D_ + kk * 32 + sc * 4;
            load_lds16(g, Sbuf[buf] + rb * 1024);   // dst wave-uniform
        }
        #pragma unroll
        for (int f2 = 0; f2 < 2; ++f2) {
            int f     = w * 2 + f2;          // 0..9
            int plane = f / 5, ct = f % 5;
            const ushort* g = Wf + (size_t)plane * PLANE_STRIDE
                                 + (ct * NKK + kk) * FRAG + lane * 8;
            load_lds16(g, Sbuf[buf] + A_BYTES + f * 1024);
        }
    };

    f32x4 acc[2][5];
    #pragma unroll
    for (int t = 0; t < 2; ++t)
        #pragma unroll
        for (int ct = 0; ct < 5; ++ct)
            acc[t][ct] = (f32x4){0.f, 0.f, 0.f, 0.f};

    auto body = [&](int buf) {
        const float*  Ab = (const float*)(Sbuf[buf]);
        const ushort* Bb = (const ushort*)(Sbuf[buf] + A_BYTES);
        f16x8 a1f[2], a2f[2];
        #pragma unroll
        for (int t = 0; t < 2; ++t) {
            int rowl = w * 32 + t * 16 + n;
            int sw   = n & 7;                // rowl&7 == n&7 (base mult of 16)
            float4 f0 = *(const float4*)(Ab + rowl * 32 + (((2 * q)     ^ sw) * 4));
            float4 f1 = *(const float4*)(Ab + rowl * 32 + (((2 * q + 1) ^ sw) * 4));
            float v[8] = {f0.x, f0.y, f0.z, f0.w, f1.x, f1.y, f1.z, f1.w};
            #pragma unroll
            for (int j = 0; j < 8; ++j) {
                _Float16 h = (_Float16)v[j];
                a1f[t][j] = h;
                a2f[t][j] = (_Float16)(v[j] - (float)h);
            }
        }
        #pragma unroll
        for (int ct = 0; ct < 5; ++ct) {
            f16x8 b1 = *(const f16x8*)(Bb + ct * 512       + lane * 8);
            f16x8 b2 = *(const f16x8*)(Bb + (5 + ct) * 512 + lane * 8);
            acc[0][ct] = __builtin_amdgcn_mfma_f32_16x16x32_f16(a1f[0], b1, acc[0][ct], 0, 0, 0);
            acc[0][ct] = __builtin_amdgcn_mfma_f32_16x16x32_f16(a2f[0], b1, acc[0][ct], 0, 0, 0);
            acc[0][ct] = __builtin_amdgcn_mfma_f32_16x16x32_f16(a1f[0], b2, acc[0][ct], 0, 0, 0);
            acc[1][ct] = __builtin_amdgcn_mfma_f32_16x16x32_f16(a1f[1], b1, acc[1][ct], 0, 0, 0);
            acc[1][ct] = __builtin_amdgcn_mfma_f32_16x16x32_f16(a2f[1], b1, acc[1][ct], 0, 0, 0);
            acc[1][ct] = __builtin_amdgcn_mfma_f32_16x16x32_f16(a1f[1], b2, acc[1][ct], 0, 0, 0);
        }
    };

    // prologue: slices 0,1 in flight (12 loads)
    stage(0, 0);
    stage(1, 1);

    for (int kk = 0; kk < 15; ++kk) {
        WAITVM(6);                           // own slice-k loads retired
        __builtin_amdgcn_s_barrier();        // everyone's slice k is in LDS
        if (kk <= 13) stage((kk + 2) % 3, kk + 2);  // overwrites buf read @ kk-1
        body(kk % 3);
    }
    WAITVM(0);                               // last slice (15)
    __builtin_amdgcn_s_barrier();
    body(0);                                 // 15 % 3 == 0

    // ---- epilogue: bias + argmax + softmax + nontemporal stores ----
    #pragma unroll
    for (int t = 0; t < 2; ++t) {
        float x[5][4];
        #pragma unroll
        for (int ct = 0; ct < 5; ++ct) {
            int c = ct * 16 + n;
            bool valid = (c < C_);
            float bv = valid ? bias[c] : 0.f;
            #pragma unroll
            for (int r = 0; r < 4; ++r)
                x[ct][r] = valid ? (acc[t][ct][r] + bv) : -INFINITY;
        }
        float av[4]; int ai[4];
        #pragma unroll
        for (int r = 0; r < 4; ++r) {
            av[r] = x[0][r]; ai[r] = n;
            #pragma unroll
            for (int ct = 1; ct < 5; ++ct) {
                int c = ct * 16 + n;
                if (x[ct][r] > av[r]) { av[r] = x[ct][r]; ai[r] = c; }
            }
        }
        #pragma unroll
        for (int off = 8; off >= 1; off >>= 1) {
            #pragma unroll
            for (int r = 0; r < 4; ++r) {
                float ov = __shfl_xor(av[r], off, 16);
                int   oi = __shfl_xor(ai[r], off, 16);
                if (ov > av[r] || (ov == av[r] && oi < ai[r])) { av[r] = ov; ai[r] = oi; }
            }
        }
        float s[4] = {0.f, 0.f, 0.f, 0.f};
        #pragma unroll
        for (int ct = 0; ct < 5; ++ct)
            #pragma unroll
            for (int r = 0; r < 4; ++r) {
                x[ct][r] = __expf(x[ct][r] - av[r]);   // -INF -> 0
                s[r] += x[ct][r];
            }
        #pragma unroll
        for (int off = 8; off >= 1; off >>= 1)
            #pragma unroll
            for (int r = 0; r < 4; ++r) s[r] += __shfl_xor(s[r], off, 16);

        const size_t growb = (size_t)blockIdx.x * ROWS_PB + w * 32 + t * 16 + q * 4;
        #pragma unroll
        for (int r = 0; r < 4; ++r) {
            float inv = 1.f / s[r];
            float* op = probs + (growb + r) * C_;
            #pragma unroll
            for (int ct = 0; ct < 5; ++ct) {
                int c = ct * 16 + n;
                if (c < C_) __builtin_nontemporal_store(x[ct][r] * inv, op + c);
            }
        }
        if (n == 0) {
            int rl = w * 32 + t * 16 + q * 4;
            #pragma unroll
            for (int r = 0; r < 4; ++r) {
                int rr = rl + r;
                best_s[rr / T_][rr % T_] = ai[r];
            }
        }
    }
    __syncthreads();

    // in-block CTC greedy decode (2 batch elements)
    if (tid < 2) {
        const int* bs = best_s[tid];
        float* op = lab + ((size_t)blockIdx.x * 2 + tid) * PRED_;
        int prev = -1, pos = 0;
        for (int t2 = 0; t2 < T_; ++t2) {
            int v = bs[t2];
            if (v != BLANK_ && v != prev) {
                if (pos < PRED_) op[pos] = (float)v;
                ++pos;
            }
            prev = v;
        }
        for (int i2 = (pos < PRED_ ? pos : PRED_); i2 < PRED_; ++i2) op[i2] = -1.f;
    }
}

extern "C" void kernel_launch(void* const* d_in, const int* in_sizes, int n_in,
                              void* d_out, int out_size, void* d_ws, size_t ws_size,
                              hipStream_t stream) {
    const float* feat = (const float*)d_in[0];   // fp32 [1024,80,512]
    const float* W    = (const float*)d_in[1];   // fp32 [512,78]
    const float* bias = (const float*)d_in[2];   // fp32 [78]
    // d_in[3]=y, d_in[4]=times : unused
    float*  probs = (float*)d_out;
    float*  lab   = probs + (size_t)B_ * T_ * C_;
    ushort* Wf    = (ushort*)d_ws;               // 163840 B scratch

    hipLaunchKernelGGL(prep_w, dim3(320), dim3(256), 0, stream, W, Wf);
    hipLaunchKernelGGL(gemm_ctc, dim3(B_ / 2), dim3(320), 0, stream,
                       feat, Wf, bias, probs, lab);
}